// Round 4
// baseline (966.761 us; speedup 1.0000x reference)
//
#include <hip/hip_runtime.h>
#include <math.h>

#define NB 64
#define NP 196
#define ND 256
#define NBP (NB * NP)   // 12544

typedef __bf16 v8bf __attribute__((ext_vector_type(8)));
typedef __bf16 v4bf __attribute__((ext_vector_type(4)));
typedef float f32x16 __attribute__((ext_vector_type(16)));

// ws layout (fast path), bytes:
//   inv1   @ 0          : 12544 f32
//   inv2   @ 50176      : 12544 f32
//   sim12  @ 100352     : 4096  f32
//   t1sw   @ 116736     : 98 tiles x 4 kc x (128x64 bf16 swizzled LDS image, 16KB) = 6422528 B
//   t2sw   @ 6539264    : 64 panels x 4 kc x (256x64 bf16 swizzled LDS image, 32KB) = 8388608 B
//   parts  @ 14927872   : 64*4*196 u64 = 401408 B
#define WS_T1SW   116736
#define WS_T2SW   6539264
#define WS_PARTS  14927872
#define WS_NEED   15329280

// ---------------------------------------------------------------------------
// packed (value,index) for argmax with np first-occurrence tie-break
// ---------------------------------------------------------------------------
__device__ __forceinline__ unsigned int fmono(float v) {
    unsigned int u = __float_as_uint(v);
    return (u & 0x80000000u) ? ~u : (u | 0x80000000u);
}
__device__ __forceinline__ unsigned long long packVI(float v, int idx) {
    return ((unsigned long long)fmono(v) << 32) | (unsigned int)(~idx);
}

// async global -> LDS, 16 bytes per lane (global_load_lds_dwordx4)
__device__ __forceinline__ void gl_lds16(void* lds, const void* gp) {
    __builtin_amdgcn_global_load_lds(
        (const __attribute__((address_space(1))) unsigned int*)gp,
        (__attribute__((address_space(3))) unsigned int*)lds, 16, 0, 0);
}

// ===========================================================================
// FAST PATH
// ===========================================================================

// Kernel 1: per-row norm; write normalized bf16 rows directly in the
// per-(tile,kc) swizzled LDS-image layout so the MFMA kernel can stage with
// linear global_load_lds (rule: linear dest + pre-swizzled source + swz read).
__global__ void filip_prep2(const float* __restrict__ t1, const float* __restrict__ t2,
                            float* __restrict__ inv1, float* __restrict__ inv2,
                            float* __restrict__ sim12,
                            char* __restrict__ t1sw, char* __restrict__ t2sw) {
    int id = blockIdx.x;             // 0 .. NBP + NB*256 - 1
    int lane = threadIdx.x;          // 0..63
    if (id < NB) sim12[id * NB + lane] = 0.0f;
    int kc = lane >> 4;              // 0..3 (K chunk of 64)
    int k8 = (lane & 15) * 8;        // byte col within chunk row (8B granule)
    if (id < NBP) {
        const float* src = t1 + (size_t)id * ND;
        float4 v = reinterpret_cast<const float4*>(src)[lane];
        float ss = v.x * v.x + v.y * v.y + v.z * v.z + v.w * v.w;
        #pragma unroll
        for (int off = 32; off > 0; off >>= 1) ss += __shfl_xor(ss, off, 64);
        float inv = 1.0f / fmaxf(sqrtf(ss), 1e-12f);
        if (lane == 0) inv1[id] = inv;
        v4bf o;
        o[0] = (__bf16)(v.x * inv); o[1] = (__bf16)(v.y * inv);
        o[2] = (__bf16)(v.z * inv); o[3] = (__bf16)(v.w * inv);
        int bRow = id >> 7, r = id & 127;
        char* dst = t1sw + (size_t)(bRow * 4 + kc) * 16384
                         + r * 128 + (k8 ^ ((r & 7) << 4));
        *reinterpret_cast<v4bf*>(dst) = o;
    } else {
        int pid = id - NBP;          // 0..16383
        int b2 = pid >> 8, r = pid & 255;
        char* dst = t2sw + (size_t)(b2 * 4 + kc) * 32768
                         + r * 128 + (k8 ^ ((r & 7) << 4));
        if (r < NP) {
            const float* src = t2 + (size_t)(b2 * NP + r) * ND;
            float4 v = reinterpret_cast<const float4*>(src)[lane];
            float ss = v.x * v.x + v.y * v.y + v.z * v.z + v.w * v.w;
            #pragma unroll
            for (int off = 32; off > 0; off >>= 1) ss += __shfl_xor(ss, off, 64);
            float inv = 1.0f / fmaxf(sqrtf(ss), 1e-12f);
            if (lane == 0) inv2[b2 * NP + r] = inv;
            v4bf o;
            o[0] = (__bf16)(v.x * inv); o[1] = (__bf16)(v.y * inv);
            o[2] = (__bf16)(v.z * inv); o[3] = (__bf16)(v.w * inv);
            *reinterpret_cast<v4bf*>(dst) = o;
        } else {
            v4bf z; z[0] = z[1] = z[2] = z[3] = (__bf16)0.0f;
            *reinterpret_cast<v4bf*>(dst) = z;
        }
    }
}

// Kernel 2: bf16 MFMA mean-of-rowmax, global_load_lds staging.
#define BM 128
#define BN 256
#define BK 64

__global__ __launch_bounds__(256, 3)
void filip_mfma3(const char* __restrict__ t1sw, const char* __restrict__ t2sw,
                 float* __restrict__ sim12)
{
    __shared__ __align__(16) char Asb[BM * BK * 2];   // 16 KB swizzled image
    __shared__ __align__(16) char Bsb[BN * BK * 2];   // 32 KB
    __shared__ float rmx[2][BM];

    // XCD-aware bijection with A-tile reuse: XCD x = n&7 owns b2 in [8x,8x+8);
    // b2 varies innermost so one A-tile is reused 8x while 8 B-panels (1MB)
    // stay L2-resident.
    int n = blockIdx.x + 98 * blockIdx.y;   // 0..6271
    int x = n & 7, local = n >> 3;          // local 0..783
    const int bRow = local >> 3;            // 0..97
    const int b2   = x * 8 + (local & 7);   // 0..63

    const int tid  = threadIdx.x;
    const int lane = tid & 63, wave = tid >> 6;
    const int wr = wave >> 1, wc = wave & 1;
    const int ln = lane & 31, hi = lane >> 5;

    const char* Ab = t1sw + (size_t)bRow * 4 * 16384;
    const char* Bb = t2sw + (size_t)b2 * 4 * 32768;

    f32x16 acc[2][4];
    #pragma unroll
    for (int mt = 0; mt < 2; ++mt)
        #pragma unroll
        for (int nt = 0; nt < 4; ++nt)
            #pragma unroll
            for (int r = 0; r < 16; ++r) acc[mt][nt][r] = 0.0f;

    for (int kc = 0; kc < 4; ++kc) {
        __syncthreads();   // previous chunk's reads complete before overwrite
        // stage A: 16KB linear copy (4 x 1KB per wave)
        #pragma unroll
        for (int i = 0; i < 4; ++i) {
            int off = i * 4096 + tid * 16;
            gl_lds16(Asb + off, Ab + kc * 16384 + off);
        }
        // stage B: 32KB linear copy (8 x 1KB per wave)
        #pragma unroll
        for (int i = 0; i < 8; ++i) {
            int off = i * 4096 + tid * 16;
            gl_lds16(Bsb + off, Bb + kc * 32768 + off);
        }
        __syncthreads();   // drains vmcnt -> LDS images complete
        #pragma unroll
        for (int ks = 0; ks < 4; ++ks) {
            const int kb = ks * 32 + hi * 16;   // byte col in LDS row
            v8bf af[2], bfr[4];
            #pragma unroll
            for (int mt = 0; mt < 2; ++mt) {
                int r = wr * 64 + mt * 32 + ln;
                af[mt] = *reinterpret_cast<const v8bf*>(
                    Asb + r * 128 + (kb ^ ((r & 7) << 4)));
            }
            #pragma unroll
            for (int nt = 0; nt < 4; ++nt) {
                int c = wc * 128 + nt * 32 + ln;
                bfr[nt] = *reinterpret_cast<const v8bf*>(
                    Bsb + c * 128 + (kb ^ ((c & 7) << 4)));
            }
            #pragma unroll
            for (int mt = 0; mt < 2; ++mt)
                #pragma unroll
                for (int nt = 0; nt < 4; ++nt)
                    acc[mt][nt] = __builtin_amdgcn_mfma_f32_32x32x16_bf16(
                        af[mt], bfr[nt], acc[mt][nt], 0, 0, 0);
        }
    }

    // fused rowmax; C/D layout: col = lane&31, row = (r&3) + 8*(r>>2) + 4*hi
    #pragma unroll
    for (int mt = 0; mt < 2; ++mt) {
        float t[16];
        #pragma unroll
        for (int r = 0; r < 16; ++r) {
            float m = fmaxf(fmaxf(acc[mt][0][r], acc[mt][1][r]),
                            fmaxf(acc[mt][2][r], acc[mt][3][r]));
            #pragma unroll
            for (int off = 1; off <= 16; off <<= 1)
                m = fmaxf(m, __shfl_xor(m, off, 64));
            t[r] = m;
        }
        if (ln == 0) {
            #pragma unroll
            for (int r = 0; r < 16; ++r) {
                int row = wr * 64 + mt * 32 + (r & 3) + 8 * (r >> 2) + 4 * hi;
                rmx[wc][row] = t[r];
            }
        }
    }
    __syncthreads();
    if (tid < BM) {
        float m = fmaxf(rmx[0][tid], rmx[1][tid]);
        int grow = bRow * BM + tid;
        int b1 = grow / NP;
        int fb = (bRow * BM) / NP;
        float v0 = (b1 == fb) ? m : 0.0f;
        float v1 = (b1 != fb) ? m : 0.0f;
        #pragma unroll
        for (int off = 1; off < 64; off <<= 1) {
            v0 += __shfl_xor(v0, off, 64);
            v1 += __shfl_xor(v1, off, 64);
        }
        if (lane == 0) {
            atomicAdd(&sim12[fb * NB + b2], v0);
            int lb = (bRow * BM + BM - 1) / NP;
            if (lb != fb) atomicAdd(&sim12[lb * NB + b2], v1);
        }
    }
}

// Kernel 3: fp32-exact diagonal blocks, 4 blocks per batch (49 rows each).
__global__ __launch_bounds__(256)
void filip_diag4(const float* __restrict__ t1, const float* __restrict__ t2,
                 const float* __restrict__ inv1, const float* __restrict__ inv2,
                 unsigned long long* __restrict__ parts,
                 float* __restrict__ out)
{
    const int q = blockIdx.x;          // 0..3 (row quarter)
    const int b = blockIdx.y;          // 0..63
    const int r0 = q * 49;
    const int tid = threadIdx.x;
    const int tx = tid & 15, ty = tid >> 4;

    __shared__ float smemF[2176 + 8320];       // As[32][68] + Bs[32][260]
    float* As = smemF;
    float* Bs = smemF + 2176;
    unsigned long long* colP = reinterpret_cast<unsigned long long*>(smemF); // reuse

    const float* Ap = t1 + (size_t)b * NP * ND;
    const float* Bp = t2 + (size_t)b * NP * ND;
    const float* ia = inv1 + b * NP;
    const float* ib = inv2 + b * NP;

    float acc[4][4][4];
    #pragma unroll
    for (int i = 0; i < 4; ++i)
        #pragma unroll
        for (int j = 0; j < 4; ++j)
            #pragma unroll
            for (int l = 0; l < 4; ++l) acc[i][j][l] = 0.0f;

    for (int kc = 0; kc < 8; ++kc) {
        __syncthreads();
        #pragma unroll
        for (int i = 0; i < 2; ++i) {
            int f4 = tid + 256 * i;            // 0..511
            int row = f4 >> 3, k4 = f4 & 7;
            float4 v = make_float4(0.f, 0.f, 0.f, 0.f);
            if (row < 49) {
                v = *reinterpret_cast<const float4*>(Ap + (size_t)(r0 + row) * ND + kc * 32 + 4 * k4);
                float s = ia[r0 + row];
                v.x *= s; v.y *= s; v.z *= s; v.w *= s;
            }
            As[(4 * k4 + 0) * 68 + row] = v.x;
            As[(4 * k4 + 1) * 68 + row] = v.y;
            As[(4 * k4 + 2) * 68 + row] = v.z;
            As[(4 * k4 + 3) * 68 + row] = v.w;
        }
        #pragma unroll
        for (int i = 0; i < 8; ++i) {
            int f4 = tid + 256 * i;            // 0..2047
            int col = f4 >> 3, k4 = f4 & 7;
            float4 v = make_float4(0.f, 0.f, 0.f, 0.f);
            if (col < NP) {
                v = *reinterpret_cast<const float4*>(Bp + (size_t)col * ND + kc * 32 + 4 * k4);
                float s = ib[col];
                v.x *= s; v.y *= s; v.z *= s; v.w *= s;
            }
            Bs[(4 * k4 + 0) * 260 + col] = v.x;
            Bs[(4 * k4 + 1) * 260 + col] = v.y;
            Bs[(4 * k4 + 2) * 260 + col] = v.z;
            Bs[(4 * k4 + 3) * 260 + col] = v.w;
        }
        __syncthreads();
        #pragma unroll 4
        for (int k = 0; k < 32; ++k) {
            float a0 = As[k * 68 + 4 * ty + 0];
            float a1 = As[k * 68 + 4 * ty + 1];
            float a2 = As[k * 68 + 4 * ty + 2];
            float a3 = As[k * 68 + 4 * ty + 3];
            float4 bq[4];
            #pragma unroll
            for (int j = 0; j < 4; ++j)
                bq[j] = *reinterpret_cast<const float4*>(&Bs[k * 260 + 4 * tx + 64 * j]);
            #pragma unroll
            for (int j = 0; j < 4; ++j) {
                acc[0][j][0] = fmaf(a0, bq[j].x, acc[0][j][0]);
                acc[0][j][1] = fmaf(a0, bq[j].y, acc[0][j][1]);
                acc[0][j][2] = fmaf(a0, bq[j].z, acc[0][j][2]);
                acc[0][j][3] = fmaf(a0, bq[j].w, acc[0][j][3]);
                acc[1][j][0] = fmaf(a1, bq[j].x, acc[1][j][0]);
                acc[1][j][1] = fmaf(a1, bq[j].y, acc[1][j][1]);
                acc[1][j][2] = fmaf(a1, bq[j].z, acc[1][j][2]);
                acc[1][j][3] = fmaf(a1, bq[j].w, acc[1][j][3]);
                acc[2][j][0] = fmaf(a2, bq[j].x, acc[2][j][0]);
                acc[2][j][1] = fmaf(a2, bq[j].y, acc[2][j][1]);
                acc[2][j][2] = fmaf(a2, bq[j].z, acc[2][j][2]);
                acc[2][j][3] = fmaf(a2, bq[j].w, acc[2][j][3]);
                acc[3][j][0] = fmaf(a3, bq[j].x, acc[3][j][0]);
                acc[3][j][1] = fmaf(a3, bq[j].y, acc[3][j][1]);
                acc[3][j][2] = fmaf(a3, bq[j].z, acc[3][j][2]);
                acc[3][j][3] = fmaf(a3, bq[j].w, acc[3][j][3]);
            }
        }
    }

    // row argmax (idx_to_keep1_2)
    #pragma unroll
    for (int i = 0; i < 4; ++i) {
        unsigned long long best = 0ull;
        #pragma unroll
        for (int j = 0; j < 4; ++j)
            #pragma unroll
            for (int l = 0; l < 4; ++l) {
                int c = 64 * j + 4 * tx + l;
                if (c < NP) {
                    unsigned long long p = packVI(acc[i][j][l], c);
                    if (p > best) best = p;
                }
            }
        #pragma unroll
        for (int off = 1; off < 16; off <<= 1) {
            unsigned long long o = __shfl_xor(best, off, 16);
            if (o > best) best = o;
        }
        int rl = 4 * ty + i;
        if (tx == 0 && rl < 49)
            out[1 + b * NP + r0 + rl] = (float)(unsigned int)(~best);
    }

    // col argmax partials (idx_to_keep2_1)
    __syncthreads();
    #pragma unroll
    for (int j = 0; j < 4; ++j)
        #pragma unroll
        for (int l = 0; l < 4; ++l) {
            unsigned long long best = 0ull;
            #pragma unroll
            for (int i = 0; i < 4; ++i) {
                int rl = 4 * ty + i;
                if (rl < 49) {
                    unsigned long long p = packVI(acc[i][j][l], r0 + rl);
                    if (p > best) best = p;
                }
            }
            colP[ty * 256 + 64 * j + 4 * tx + l] = best;
        }
    __syncthreads();
    {
        unsigned long long best = 0ull;
        #pragma unroll
        for (int y = 0; y < 16; ++y) {
            unsigned long long o = colP[y * 256 + tid];
            if (o > best) best = o;
        }
        if (tid < NP) parts[(b * 4 + q) * NP + tid] = best;
    }
}

// Kernel 4: merge the 4 quarter partials -> idx_to_keep2_1
__global__ void filip_fin(const unsigned long long* __restrict__ parts,
                          float* __restrict__ out) {
    int id = blockIdx.x * 256 + threadIdx.x;   // 49*256 = 12544
    int b = id / NP, c = id - b * NP;
    unsigned long long best = 0ull;
    #pragma unroll
    for (int qq = 0; qq < 4; ++qq) {
        unsigned long long o = parts[(b * 4 + qq) * NP + c];
        if (o > best) best = o;
    }
    out[1 + NBP + id] = (float)(unsigned int)(~best);
}

// Kernel 5: InfoNCE loss. sim12 holds SUMS of rowmax -> scale by 10/196.
__global__ void filip_loss(const float* __restrict__ sim12,
                           float* __restrict__ out) {
    int i = threadIdx.x;  // 0..63
    const float SC = 10.0f / 196.0f;
    const float* row = sim12 + i * NB;
    float mx = -3.0e38f;
    for (int j = 0; j < NB; ++j) mx = fmaxf(mx, row[j] * SC);
    float s = 0.0f;
    for (int j = 0; j < NB; ++j) s += expf(row[j] * SC - mx);
    float lse = mx + logf(s);
    float li = lse - row[i] * SC;
    #pragma unroll
    for (int off = 32; off > 0; off >>= 1)
        li += __shfl_xor(li, off, 64);
    if (i == 0) out[0] = li / 64.0f;
}

// ===========================================================================
// FALLBACK PATH (verbatim round-2, known-passing) — used if ws too small
// ===========================================================================
__global__ void filip_norms(const float* __restrict__ t1,
                            const float* __restrict__ t2,
                            float* __restrict__ inv1,
                            float* __restrict__ inv2,
                            float* __restrict__ sim12) {
    int row = blockIdx.x;
    int lane = threadIdx.x;
    if (row < NB) sim12[row * NB + lane] = 0.0f;
    const float* src; float* dst; int r;
    if (row < NBP) { src = t1; dst = inv1; r = row; }
    else           { src = t2; dst = inv2; r = row - NBP; }
    float4 v = reinterpret_cast<const float4*>(src + (size_t)r * ND)[lane];
    float ss = v.x * v.x + v.y * v.y + v.z * v.z + v.w * v.w;
    #pragma unroll
    for (int off = 32; off > 0; off >>= 1)
        ss += __shfl_xor(ss, off, 64);
    if (lane == 0)
        dst[r] = 1.0f / fmaxf(sqrtf(ss), 1e-12f);
}

__device__ __forceinline__ v8bf cvt8(float4 a, float4 b, float s) {
    v8bf v;
    v[0] = (__bf16)(a.x * s); v[1] = (__bf16)(a.y * s);
    v[2] = (__bf16)(a.z * s); v[3] = (__bf16)(a.w * s);
    v[4] = (__bf16)(b.x * s); v[5] = (__bf16)(b.y * s);
    v[6] = (__bf16)(b.z * s); v[7] = (__bf16)(b.w * s);
    return v;
}

__global__ __launch_bounds__(256, 2)
void filip_mfma(const float* __restrict__ t1, const float* __restrict__ t2,
                const float* __restrict__ inv1, const float* __restrict__ inv2,
                float* __restrict__ sim12)
{
    __shared__ unsigned short Asb[BM * BK];
    __shared__ unsigned short Bsb[BN * BK];
    __shared__ float rmx[2][BM];

    const int bRow = blockIdx.x;
    const int b2   = blockIdx.y;
    const int tid  = threadIdx.x;
    const int lane = tid & 63, wave = tid >> 6;
    const int wr = wave >> 1, wc = wave & 1;
    const int ln = lane & 31, hi = lane >> 5;

    const float* Abase = t1 + (size_t)bRow * BM * ND;
    const float* Bbase = t2 + (size_t)b2 * NP * ND;

    f32x16 acc[2][4];
    #pragma unroll
    for (int mt = 0; mt < 2; ++mt)
        #pragma unroll
        for (int nt = 0; nt < 4; ++nt)
            #pragma unroll
            for (int r = 0; r < 16; ++r) acc[mt][nt][r] = 0.0f;

    for (int kc = 0; kc < 4; ++kc) {
        __syncthreads();
        #pragma unroll
        for (int i = 0; i < 4; ++i) {
            int flat = (i * 256 + tid) * 8;
            int r = flat >> 6, k0 = flat & 63;
            const float* gp = Abase + (size_t)r * ND + kc * BK + k0;
            float4 f0 = *reinterpret_cast<const float4*>(gp);
            float4 f1 = *reinterpret_cast<const float4*>(gp + 4);
            float s = inv1[bRow * BM + r];
            v8bf v = cvt8(f0, f1, s);
            int off = r * 128 + ((k0 * 2) ^ ((r & 7) << 4));
            *reinterpret_cast<v8bf*>(reinterpret_cast<char*>(Asb) + off) = v;
        }
        #pragma unroll
        for (int i = 0; i < 8; ++i) {
            int flat = (i * 256 + tid) * 8;
            int r = flat >> 6, k0 = flat & 63;
            v8bf v;
            if (r < NP) {
                const float* gp = Bbase + (size_t)r * ND + kc * BK + k0;
                float4 f0 = *reinterpret_cast<const float4*>(gp);
                float4 f1 = *reinterpret_cast<const float4*>(gp + 4);
                float s = inv2[b2 * NP + r];
                v = cvt8(f0, f1, s);
            } else {
                #pragma unroll
                for (int j = 0; j < 8; ++j) v[j] = (__bf16)0.0f;
            }
            int off = r * 128 + ((k0 * 2) ^ ((r & 7) << 4));
            *reinterpret_cast<v8bf*>(reinterpret_cast<char*>(Bsb) + off) = v;
        }
        __syncthreads();
        #pragma unroll
        for (int ks = 0; ks < 4; ++ks) {
            const int kb = ks * 32 + hi * 16;
            v8bf af[2], bfr[4];
            #pragma unroll
            for (int mt = 0; mt < 2; ++mt) {
                int r = wr * 64 + mt * 32 + ln;
                af[mt] = *reinterpret_cast<const v8bf*>(
                    reinterpret_cast<const char*>(Asb) + r * 128 + (kb ^ ((r & 7) << 4)));
            }
            #pragma unroll
            for (int nt = 0; nt < 4; ++nt) {
                int c = wc * 128 + nt * 32 + ln;
                bfr[nt] = *reinterpret_cast<const v8bf*>(
                    reinterpret_cast<const char*>(Bsb) + c * 128 + (kb ^ ((c & 7) << 4)));
            }
            #pragma unroll
            for (int mt = 0; mt < 2; ++mt)
                #pragma unroll
                for (int nt = 0; nt < 4; ++nt)
                    acc[mt][nt] = __builtin_amdgcn_mfma_f32_32x32x16_bf16(
                        af[mt], bfr[nt], acc[mt][nt], 0, 0, 0);
        }
    }

    #pragma unroll
    for (int mt = 0; mt < 2; ++mt) {
        float t[16];
        #pragma unroll
        for (int r = 0; r < 16; ++r) {
            float m = fmaxf(fmaxf(acc[mt][0][r], acc[mt][1][r]),
                            fmaxf(acc[mt][2][r], acc[mt][3][r]));
            #pragma unroll
            for (int off = 1; off <= 16; off <<= 1)
                m = fmaxf(m, __shfl_xor(m, off, 64));
            t[r] = m;
        }
        if (ln == 0) {
            #pragma unroll
            for (int r = 0; r < 16; ++r) {
                int row = wr * 64 + mt * 32 + (r & 3) + 8 * (r >> 2) + 4 * hi;
                rmx[wc][row] = t[r];
            }
        }
    }
    __syncthreads();
    if (tid < BM) {
        float m = fmaxf(rmx[0][tid], rmx[1][tid]);
        int grow = bRow * BM + tid;
        int b1 = grow / NP;
        int fb = (bRow * BM) / NP;
        float v0 = (b1 == fb) ? m : 0.0f;
        float v1 = (b1 != fb) ? m : 0.0f;
        #pragma unroll
        for (int off = 1; off < 64; off <<= 1) {
            v0 += __shfl_xor(v0, off, 64);
            v1 += __shfl_xor(v1, off, 64);
        }
        if (lane == 0) {
            atomicAdd(&sim12[fb * NB + b2], v0);
            int lb = (bRow * BM + BM - 1) / NP;
            if (lb != fb) atomicAdd(&sim12[lb * NB + b2], v1);
        }
    }
}

__global__ __launch_bounds__(256)
void filip_diag(const float* __restrict__ t1, const float* __restrict__ t2,
                const float* __restrict__ inv1, const float* __restrict__ inv2,
                float* __restrict__ out)
{
    const int b = blockIdx.x;
    const int tid = threadIdx.x;
    const int tx = tid & 15, ty = tid >> 4;

    __shared__ float As2[16][209];
    __shared__ float Bs2[16][65];
    __shared__ float colV[16][65];
    __shared__ int   colI[16][65];

    const float* Ap = t1 + (size_t)b * NP * ND;
    const float* Bp = t2 + (size_t)b * NP * ND;
    const float* ia = inv1 + b * NP;
    const float* ib = inv2 + b * NP;

    float rmax[13];
    int   ridx[13];
    #pragma unroll
    for (int m = 0; m < 13; ++m) { rmax[m] = -3.0e38f; ridx[m] = 1 << 30; }

    for (int tile = 0; tile < 4; ++tile) {
        float acc[13][4];
        #pragma unroll
        for (int m = 0; m < 13; ++m)
            #pragma unroll
            for (int n = 0; n < 4; ++n) acc[m][n] = 0.0f;

        for (int kk = 0; kk < 16; ++kk) {
            __syncthreads();
            #pragma unroll
            for (int i = 0; i < 13; ++i) {
                int e = tid + 256 * i;
                int p1 = e >> 4, k = e & 15;
                float v = 0.0f;
                if (p1 < NP) v = Ap[p1 * ND + kk * 16 + k] * ia[p1];
                As2[k][p1] = v;
            }
            #pragma unroll
            for (int i = 0; i < 4; ++i) {
                int e = tid + 256 * i;
                int pl = e >> 4, k = e & 15;
                int p2 = tile * 64 + pl;
                float v = 0.0f;
                if (p2 < NP) v = Bp[p2 * ND + kk * 16 + k] * ib[p2];
                Bs2[k][pl] = v;
            }
            __syncthreads();
            #pragma unroll 4
            for (int k = 0; k < 16; ++k) {
                float a[13], bq[4];
                #pragma unroll
                for (int m = 0; m < 13; ++m) a[m] = As2[k][ty + 16 * m];
                #pragma unroll
                for (int n = 0; n < 4; ++n) bq[n] = Bs2[k][tx + 16 * n];
                #pragma unroll
                for (int m = 0; m < 13; ++m)
                    #pragma unroll
                    for (int n = 0; n < 4; ++n)
                        acc[m][n] = fmaf(a[m], bq[n], acc[m][n]);
            }
        }

        #pragma unroll
        for (int n = 0; n < 4; ++n) {
            int c = tile * 64 + tx + 16 * n;
            if (c < NP) {
                #pragma unroll
                for (int m = 0; m < 13; ++m) {
                    float v = acc[m][n];
                    if (v > rmax[m] || (v == rmax[m] && c < ridx[m])) {
                        rmax[m] = v; ridx[m] = c;
                    }
                }
            }
        }

        #pragma unroll
        for (int n = 0; n < 4; ++n) {
            float bv = -3.0e38f; int bi = 1 << 30;
            #pragma unroll
            for (int m = 0; m < 13; ++m) {
                int row = ty + 16 * m;
                if (row < NP) {
                    float v = acc[m][n];
                    if (v > bv || (v == bv && row < bi)) { bv = v; bi = row; }
                }
            }
            colV[ty][tx + 16 * n] = bv;
            colI[ty][tx + 16 * n] = bi;
        }
        __syncthreads();
        if (tid < 64) {
            int c = tile * 64 + tid;
            if (c < NP) {
                float bv = -3.0e38f; int bi = 1 << 30;
                #pragma unroll
                for (int y = 0; y < 16; ++y) {
                    float v = colV[y][tid]; int i2 = colI[y][tid];
                    if (v > bv || (v == bv && i2 < bi)) { bv = v; bi = i2; }
                }
                out[1 + NBP + b * NP + c] = (float)bi;
            }
        }
        __syncthreads();
    }

    #pragma unroll
    for (int m = 0; m < 13; ++m) {
        float v = rmax[m]; int ix = ridx[m];
        #pragma unroll
        for (int off = 1; off < 16; off <<= 1) {
            float ov = __shfl_xor(v, off, 16);
            int   oi = __shfl_xor(ix, off, 16);
            if (ov > v || (ov == v && oi < ix)) { v = ov; ix = oi; }
        }
        rmax[m] = v; ridx[m] = ix;
    }
    if (tx == 0) {
        #pragma unroll
        for (int m = 0; m < 13; ++m) {
            int row = ty + 16 * m;
            if (row < NP) out[1 + b * NP + row] = (float)ridx[m];
        }
    }
}

// ---------------------------------------------------------------------------
extern "C" void kernel_launch(void* const* d_in, const int* in_sizes, int n_in,
                              void* d_out, int out_size, void* d_ws, size_t ws_size,
                              hipStream_t stream) {
    const float* t1 = (const float*)d_in[0];
    const float* t2 = (const float*)d_in[1];
    float* out = (float*)d_out;
    float* ws  = (float*)d_ws;

    float* inv1  = ws;
    float* inv2  = ws + NBP;
    float* sim12 = ws + 2 * NBP;

    if (ws_size >= (size_t)WS_NEED) {
        char* t1sw = (char*)d_ws + WS_T1SW;
        char* t2sw = (char*)d_ws + WS_T2SW;
        unsigned long long* parts = (unsigned long long*)((char*)d_ws + WS_PARTS);

        filip_prep2<<<NBP + NB * 256, 64, 0, stream>>>(t1, t2, inv1, inv2, sim12, t1sw, t2sw);
        filip_mfma3<<<dim3(98, NB), 256, 0, stream>>>(t1sw, t2sw, sim12);
        filip_diag4<<<dim3(4, NB), 256, 0, stream>>>(t1, t2, inv1, inv2, parts, out);
        filip_fin<<<49, 256, 0, stream>>>(parts, out);
        filip_loss<<<1, 64, 0, stream>>>(sim12, out);
    } else {
        filip_norms<<<2 * NBP, 64, 0, stream>>>(t1, t2, inv1, inv2, sim12);
        filip_mfma<<<dim3(98, NB), 256, 0, stream>>>(t1, t2, inv1, inv2, sim12);
        filip_diag<<<NB, 256, 0, stream>>>(t1, t2, inv1, inv2, out);
        filip_loss<<<1, 64, 0, stream>>>(sim12, out);
    }
}

// Round 5
// 207.390 us; speedup vs baseline: 4.6616x; 4.6616x over previous
//
#include <hip/hip_runtime.h>
#include <math.h>

#define NB 64
#define NP 196
#define ND 256
#define NBP (NB * NP)   // 12544

typedef __bf16 v8bf __attribute__((ext_vector_type(8)));
typedef __bf16 v4bf __attribute__((ext_vector_type(4)));
typedef float f32x16 __attribute__((ext_vector_type(16)));

// ws layout (fast path), bytes:
//   inv1   @ 0          : 12544 f32
//   inv2   @ 50176      : 12544 f32
//   sim12  @ 100352     : 4096  f32
//   t1bf   @ 116736     : 12544*256 bf16 = 6422528 B (row-major)
//   t2bf   @ 6539264    : 12544*256 bf16 = 6422528 B (row-major, compact 196 rows/batch)
//   parts  @ 12961792   : 64*4*196 u64 = 401408 B
#define WS_T1BF   116736
#define WS_T2BF   6539264
#define WS_PARTS  12961792
#define WS_NEED   13363200

// ---------------------------------------------------------------------------
// packed (value,index) for argmax with np first-occurrence tie-break
// ---------------------------------------------------------------------------
__device__ __forceinline__ unsigned int fmono(float v) {
    unsigned int u = __float_as_uint(v);
    return (u & 0x80000000u) ? ~u : (u | 0x80000000u);
}
__device__ __forceinline__ unsigned long long packVI(float v, int idx) {
    return ((unsigned long long)fmono(v) << 32) | (unsigned int)(~idx);
}

// ===========================================================================
// FAST PATH
// ===========================================================================

// Kernel 1: per-row norm -> inv arrays; normalized bf16 rows (row-major).
// 256-thread blocks, one row per 64-lane group. Block 0 zeroes sim12.
__global__ __launch_bounds__(256)
void filip_prep3(const float* __restrict__ t1, const float* __restrict__ t2,
                 float* __restrict__ inv1, float* __restrict__ inv2,
                 float* __restrict__ sim12,
                 __bf16* __restrict__ t1bf, __bf16* __restrict__ t2bf) {
    const int tid = threadIdx.x;
    if (blockIdx.x == 0) {
        float4 z = make_float4(0.f, 0.f, 0.f, 0.f);
        float4* s4 = reinterpret_cast<float4*>(sim12);
        #pragma unroll
        for (int j = 0; j < 4; ++j) s4[tid * 4 + j] = z;
    }
    int row = blockIdx.x * 4 + (tid >> 6);   // 0 .. 2*NBP-1 (boundary block-aligned)
    int lane = tid & 63;
    bool is1 = row < NBP;
    int r = is1 ? row : row - NBP;
    const float* src = (is1 ? t1 : t2) + (size_t)r * ND;
    float4 v = reinterpret_cast<const float4*>(src)[lane];
    float ss = v.x * v.x + v.y * v.y + v.z * v.z + v.w * v.w;
    #pragma unroll
    for (int off = 32; off > 0; off >>= 1) ss += __shfl_xor(ss, off, 64);
    float inv = 1.0f / fmaxf(sqrtf(ss), 1e-12f);
    if (lane == 0) (is1 ? inv1 : inv2)[r] = inv;
    v4bf o;
    o[0] = (__bf16)(v.x * inv); o[1] = (__bf16)(v.y * inv);
    o[2] = (__bf16)(v.z * inv); o[3] = (__bf16)(v.w * inv);
    __bf16* dst = (is1 ? t1bf : t2bf) + (size_t)r * ND + 4 * lane;
    *reinterpret_cast<v4bf*>(dst) = o;
}

// Kernel 2: bf16 MFMA mean-of-rowmax. Reg-staged (round-3 proven path) +
// raw-barrier pipeline: ds_write(kc) -> issue global loads(kc+1) ->
// lgkmcnt(0) -> s_barrier -> MFMA compute(kc). Loads stay in flight across
// the compute phase (raw s_barrier does not drain vmcnt).
#define BM 128
#define BN 256
#define BK 64

__global__ __launch_bounds__(256, 2)
void filip_mfma4(const __bf16* __restrict__ t1bf, const __bf16* __restrict__ t2bf,
                 float* __restrict__ sim12)
{
    __shared__ __align__(16) char Asb[BM * BK * 2];   // 16 KB swizzled [row][k]
    __shared__ __align__(16) char Bsb[BN * BK * 2];   // 32 KB
    __shared__ float rmx[2][BM];

    // XCD-aware bijection with A-tile reuse: XCD x = n&7 owns b2 in [8x,8x+8);
    // b2 varies innermost -> one A-tile reused 8x back-to-back, 8 B-panels
    // (~0.8 MB) stay L2-resident per XCD.
    int n = blockIdx.x + 98 * blockIdx.y;   // 0..6271
    int x = n & 7, local = n >> 3;
    const int bRow = local >> 3;            // 0..97
    const int b2   = x * 8 + (local & 7);   // 0..63

    const int tid  = threadIdx.x;
    const int lane = tid & 63, wave = tid >> 6;
    const int wr = wave >> 1, wc = wave & 1;
    const int ln = lane & 31, hi = lane >> 5;

    const __bf16* Ab = t1bf + (size_t)bRow * BM * ND;
    const __bf16* Bb = t2bf + (size_t)b2 * NP * ND;

    f32x16 acc[2][4];
    #pragma unroll
    for (int mt = 0; mt < 2; ++mt)
        #pragma unroll
        for (int nt = 0; nt < 4; ++nt)
            #pragma unroll
            for (int r = 0; r < 16; ++r) acc[mt][nt][r] = 0.0f;

    // zero B pad rows 196..255 ONCE (never rewritten; zeros survive all kc)
    {
        v8bf z;
        #pragma unroll
        for (int j = 0; j < 8; ++j) z[j] = (__bf16)0.0f;
        #pragma unroll
        for (int i = 0; i < 2; ++i) {
            int idx = i * 256 + tid;            // 0..511 (480 used)
            if (idx < 480) {
                int r = 196 + (idx >> 3), g = idx & 7;
                *reinterpret_cast<v8bf*>(Bsb + r * 128 + ((g * 16) ^ ((r & 7) << 4))) = z;
            }
        }
    }

    // prologue: load kc=0 tile into registers
    v8bf rA[4], rB[7];
    #pragma unroll
    for (int i = 0; i < 4; ++i) {
        int idx = i * 256 + tid, r = idx >> 3, g = idx & 7;
        rA[i] = *reinterpret_cast<const v8bf*>(Ab + (size_t)r * ND + g * 8);
    }
    #pragma unroll
    for (int i = 0; i < 7; ++i) {
        int idx = i * 256 + tid, r = idx >> 3, g = idx & 7;
        if (idx < 1568)
            rB[i] = *reinterpret_cast<const v8bf*>(Bb + (size_t)r * ND + g * 8);
    }

    for (int kc = 0; kc < 4; ++kc) {
        asm volatile("" ::: "memory");
        __builtin_amdgcn_s_barrier();          // all waves done reading prev tile
        asm volatile("" ::: "memory");
        // write current tile (registers -> swizzled LDS)
        #pragma unroll
        for (int i = 0; i < 4; ++i) {
            int idx = i * 256 + tid, r = idx >> 3, g = idx & 7;
            *reinterpret_cast<v8bf*>(Asb + r * 128 + ((g * 16) ^ ((r & 7) << 4))) = rA[i];
        }
        #pragma unroll
        for (int i = 0; i < 7; ++i) {
            int idx = i * 256 + tid, r = idx >> 3, g = idx & 7;
            if (idx < 1568)
                *reinterpret_cast<v8bf*>(Bsb + r * 128 + ((g * 16) ^ ((r & 7) << 4))) = rB[i];
        }
        // prefetch next tile into regs; stays in flight across compute
        if (kc < 3) {
            #pragma unroll
            for (int i = 0; i < 4; ++i) {
                int idx = i * 256 + tid, r = idx >> 3, g = idx & 7;
                rA[i] = *reinterpret_cast<const v8bf*>(Ab + (size_t)r * ND + (kc + 1) * BK + g * 8);
            }
            #pragma unroll
            for (int i = 0; i < 7; ++i) {
                int idx = i * 256 + tid, r = idx >> 3, g = idx & 7;
                if (idx < 1568)
                    rB[i] = *reinterpret_cast<const v8bf*>(Bb + (size_t)r * ND + (kc + 1) * BK + g * 8);
            }
        }
        asm volatile("s_waitcnt lgkmcnt(0)" ::: "memory");   // own ds_writes done
        __builtin_amdgcn_s_barrier();                        // LDS tile complete
        asm volatile("" ::: "memory");
        // compute: 4 k-steps of K=16, 8 MFMA each (identical to round-3)
        #pragma unroll
        for (int ks = 0; ks < 4; ++ks) {
            const int kb = ks * 32 + hi * 16;   // byte col in LDS row
            v8bf af[2], bfr[4];
            #pragma unroll
            for (int mt = 0; mt < 2; ++mt) {
                int r = wr * 64 + mt * 32 + ln;
                af[mt] = *reinterpret_cast<const v8bf*>(
                    Asb + r * 128 + (kb ^ ((r & 7) << 4)));
            }
            #pragma unroll
            for (int nt = 0; nt < 4; ++nt) {
                int c = wc * 128 + nt * 32 + ln;
                bfr[nt] = *reinterpret_cast<const v8bf*>(
                    Bsb + c * 128 + (kb ^ ((c & 7) << 4)));
            }
            #pragma unroll
            for (int mt = 0; mt < 2; ++mt)
                #pragma unroll
                for (int nt = 0; nt < 4; ++nt)
                    acc[mt][nt] = __builtin_amdgcn_mfma_f32_32x32x16_bf16(
                        af[mt], bfr[nt], acc[mt][nt], 0, 0, 0);
        }
    }

    // fused rowmax; C/D layout: col = lane&31, row = (r&3) + 8*(r>>2) + 4*hi
    #pragma unroll
    for (int mt = 0; mt < 2; ++mt) {
        float t[16];
        #pragma unroll
        for (int r = 0; r < 16; ++r) {
            float m = fmaxf(fmaxf(acc[mt][0][r], acc[mt][1][r]),
                            fmaxf(acc[mt][2][r], acc[mt][3][r]));
            #pragma unroll
            for (int off = 1; off <= 16; off <<= 1)
                m = fmaxf(m, __shfl_xor(m, off, 64));
            t[r] = m;
        }
        if (ln == 0) {
            #pragma unroll
            for (int r = 0; r < 16; ++r) {
                int row = wr * 64 + mt * 32 + (r & 3) + 8 * (r >> 2) + 4 * hi;
                rmx[wc][row] = t[r];
            }
        }
    }
    __syncthreads();
    if (tid < BM) {
        float m = fmaxf(rmx[0][tid], rmx[1][tid]);
        int grow = bRow * BM + tid;
        int b1 = grow / NP;
        int fb = (bRow * BM) / NP;
        float v0 = (b1 == fb) ? m : 0.0f;
        float v1 = (b1 != fb) ? m : 0.0f;
        #pragma unroll
        for (int off = 1; off < 64; off <<= 1) {
            v0 += __shfl_xor(v0, off, 64);
            v1 += __shfl_xor(v1, off, 64);
        }
        if (lane == 0) {
            atomicAdd(&sim12[fb * NB + b2], v0);
            int lb = (bRow * BM + BM - 1) / NP;
            if (lb != fb) atomicAdd(&sim12[lb * NB + b2], v1);
        }
    }
}

// Kernel 3: fp32-exact diagonal blocks, 4 blocks per batch (49 rows each).
__global__ __launch_bounds__(256)
void filip_diag4(const float* __restrict__ t1, const float* __restrict__ t2,
                 const float* __restrict__ inv1, const float* __restrict__ inv2,
                 unsigned long long* __restrict__ parts,
                 float* __restrict__ out)
{
    const int q = blockIdx.x;          // 0..3 (row quarter)
    const int b = blockIdx.y;          // 0..63
    const int r0 = q * 49;
    const int tid = threadIdx.x;
    const int tx = tid & 15, ty = tid >> 4;

    __shared__ float smemF[2176 + 8320];       // As[32][68] + Bs[32][260]
    float* As = smemF;
    float* Bs = smemF + 2176;
    unsigned long long* colP = reinterpret_cast<unsigned long long*>(smemF); // reuse

    const float* Ap = t1 + (size_t)b * NP * ND;
    const float* Bp = t2 + (size_t)b * NP * ND;
    const float* ia = inv1 + b * NP;
    const float* ib = inv2 + b * NP;

    float acc[4][4][4];
    #pragma unroll
    for (int i = 0; i < 4; ++i)
        #pragma unroll
        for (int j = 0; j < 4; ++j)
            #pragma unroll
            for (int l = 0; l < 4; ++l) acc[i][j][l] = 0.0f;

    for (int kc = 0; kc < 8; ++kc) {
        __syncthreads();
        #pragma unroll
        for (int i = 0; i < 2; ++i) {
            int f4 = tid + 256 * i;            // 0..511
            int row = f4 >> 3, k4 = f4 & 7;
            float4 v = make_float4(0.f, 0.f, 0.f, 0.f);
            if (row < 49) {
                v = *reinterpret_cast<const float4*>(Ap + (size_t)(r0 + row) * ND + kc * 32 + 4 * k4);
                float s = ia[r0 + row];
                v.x *= s; v.y *= s; v.z *= s; v.w *= s;
            }
            As[(4 * k4 + 0) * 68 + row] = v.x;
            As[(4 * k4 + 1) * 68 + row] = v.y;
            As[(4 * k4 + 2) * 68 + row] = v.z;
            As[(4 * k4 + 3) * 68 + row] = v.w;
        }
        #pragma unroll
        for (int i = 0; i < 8; ++i) {
            int f4 = tid + 256 * i;            // 0..2047
            int col = f4 >> 3, k4 = f4 & 7;
            float4 v = make_float4(0.f, 0.f, 0.f, 0.f);
            if (col < NP) {
                v = *reinterpret_cast<const float4*>(Bp + (size_t)col * ND + kc * 32 + 4 * k4);
                float s = ib[col];
                v.x *= s; v.y *= s; v.z *= s; v.w *= s;
            }
            Bs[(4 * k4 + 0) * 260 + col] = v.x;
            Bs[(4 * k4 + 1) * 260 + col] = v.y;
            Bs[(4 * k4 + 2) * 260 + col] = v.z;
            Bs[(4 * k4 + 3) * 260 + col] = v.w;
        }
        __syncthreads();
        #pragma unroll 4
        for (int k = 0; k < 32; ++k) {
            float a0 = As[k * 68 + 4 * ty + 0];
            float a1 = As[k * 68 + 4 * ty + 1];
            float a2 = As[k * 68 + 4 * ty + 2];
            float a3 = As[k * 68 + 4 * ty + 3];
            float4 bq[4];
            #pragma unroll
            for (int j = 0; j < 4; ++j)
                bq[j] = *reinterpret_cast<const float4*>(&Bs[k * 260 + 4 * tx + 64 * j]);
            #pragma unroll
            for (int j = 0; j < 4; ++j) {
                acc[0][j][0] = fmaf(a0, bq[j].x, acc[0][j][0]);
                acc[0][j][1] = fmaf(a0, bq[j].y, acc[0][j][1]);
                acc[0][j][2] = fmaf(a0, bq[j].z, acc[0][j][2]);
                acc[0][j][3] = fmaf(a0, bq[j].w, acc[0][j][3]);
                acc[1][j][0] = fmaf(a1, bq[j].x, acc[1][j][0]);
                acc[1][j][1] = fmaf(a1, bq[j].y, acc[1][j][1]);
                acc[1][j][2] = fmaf(a1, bq[j].z, acc[1][j][2]);
                acc[1][j][3] = fmaf(a1, bq[j].w, acc[1][j][3]);
                acc[2][j][0] = fmaf(a2, bq[j].x, acc[2][j][0]);
                acc[2][j][1] = fmaf(a2, bq[j].y, acc[2][j][1]);
                acc[2][j][2] = fmaf(a2, bq[j].z, acc[2][j][2]);
                acc[2][j][3] = fmaf(a2, bq[j].w, acc[2][j][3]);
                acc[3][j][0] = fmaf(a3, bq[j].x, acc[3][j][0]);
                acc[3][j][1] = fmaf(a3, bq[j].y, acc[3][j][1]);
                acc[3][j][2] = fmaf(a3, bq[j].z, acc[3][j][2]);
                acc[3][j][3] = fmaf(a3, bq[j].w, acc[3][j][3]);
            }
        }
    }

    // row argmax (idx_to_keep1_2)
    #pragma unroll
    for (int i = 0; i < 4; ++i) {
        unsigned long long best = 0ull;
        #pragma unroll
        for (int j = 0; j < 4; ++j)
            #pragma unroll
            for (int l = 0; l < 4; ++l) {
                int c = 64 * j + 4 * tx + l;
                if (c < NP) {
                    unsigned long long p = packVI(acc[i][j][l], c);
                    if (p > best) best = p;
                }
            }
        #pragma unroll
        for (int off = 1; off < 16; off <<= 1) {
            unsigned long long o = __shfl_xor(best, off, 16);
            if (o > best) best = o;
        }
        int rl = 4 * ty + i;
        if (tx == 0 && rl < 49)
            out[1 + b * NP + r0 + rl] = (float)(unsigned int)(~best);
    }

    // col argmax partials (idx_to_keep2_1)
    __syncthreads();
    #pragma unroll
    for (int j = 0; j < 4; ++j)
        #pragma unroll
        for (int l = 0; l < 4; ++l) {
            unsigned long long best = 0ull;
            #pragma unroll
            for (int i = 0; i < 4; ++i) {
                int rl = 4 * ty + i;
                if (rl < 49) {
                    unsigned long long p = packVI(acc[i][j][l], r0 + rl);
                    if (p > best) best = p;
                }
            }
            colP[ty * 256 + 64 * j + 4 * tx + l] = best;
        }
    __syncthreads();
    {
        unsigned long long best = 0ull;
        #pragma unroll
        for (int y = 0; y < 16; ++y) {
            unsigned long long o = colP[y * 256 + tid];
            if (o > best) best = o;
        }
        if (tid < NP) parts[(b * 4 + q) * NP + tid] = best;
    }
}

// Kernel 4: merge the 4 quarter partials -> idx_to_keep2_1
__global__ void filip_fin(const unsigned long long* __restrict__ parts,
                          float* __restrict__ out) {
    int id = blockIdx.x * 256 + threadIdx.x;   // 49*256 = 12544
    int b = id / NP, c = id - b * NP;
    unsigned long long best = 0ull;
    #pragma unroll
    for (int qq = 0; qq < 4; ++qq) {
        unsigned long long o = parts[(b * 4 + qq) * NP + c];
        if (o > best) best = o;
    }
    out[1 + NBP + id] = (float)(unsigned int)(~best);
}

// Kernel 5: InfoNCE loss. sim12 holds SUMS of rowmax -> scale by 10/196.
__global__ void filip_loss(const float* __restrict__ sim12,
                           float* __restrict__ out) {
    int i = threadIdx.x;  // 0..63
    const float SC = 10.0f / 196.0f;
    const float* row = sim12 + i * NB;
    float mx = -3.0e38f;
    for (int j = 0; j < NB; ++j) mx = fmaxf(mx, row[j] * SC);
    float s = 0.0f;
    for (int j = 0; j < NB; ++j) s += expf(row[j] * SC - mx);
    float lse = mx + logf(s);
    float li = lse - row[i] * SC;
    #pragma unroll
    for (int off = 32; off > 0; off >>= 1)
        li += __shfl_xor(li, off, 64);
    if (i == 0) out[0] = li / 64.0f;
}

// ===========================================================================
// FALLBACK PATH (verbatim round-2, known-passing) — used if ws too small
// ===========================================================================
__global__ void filip_norms(const float* __restrict__ t1,
                            const float* __restrict__ t2,
                            float* __restrict__ inv1,
                            float* __restrict__ inv2,
                            float* __restrict__ sim12) {
    int row = blockIdx.x;
    int lane = threadIdx.x;
    if (row < NB) sim12[row * NB + lane] = 0.0f;
    const float* src; float* dst; int r;
    if (row < NBP) { src = t1; dst = inv1; r = row; }
    else           { src = t2; dst = inv2; r = row - NBP; }
    float4 v = reinterpret_cast<const float4*>(src + (size_t)r * ND)[lane];
    float ss = v.x * v.x + v.y * v.y + v.z * v.z + v.w * v.w;
    #pragma unroll
    for (int off = 32; off > 0; off >>= 1)
        ss += __shfl_xor(ss, off, 64);
    if (lane == 0)
        dst[r] = 1.0f / fmaxf(sqrtf(ss), 1e-12f);
}

__device__ __forceinline__ v8bf cvt8(float4 a, float4 b, float s) {
    v8bf v;
    v[0] = (__bf16)(a.x * s); v[1] = (__bf16)(a.y * s);
    v[2] = (__bf16)(a.z * s); v[3] = (__bf16)(a.w * s);
    v[4] = (__bf16)(b.x * s); v[5] = (__bf16)(b.y * s);
    v[6] = (__bf16)(b.z * s); v[7] = (__bf16)(b.w * s);
    return v;
}

__global__ __launch_bounds__(256, 2)
void filip_mfma(const float* __restrict__ t1, const float* __restrict__ t2,
                const float* __restrict__ inv1, const float* __restrict__ inv2,
                float* __restrict__ sim12)
{
    __shared__ unsigned short Asb[BM * BK];
    __shared__ unsigned short Bsb[BN * BK];
    __shared__ float rmx[2][BM];

    const int bRow = blockIdx.x;
    const int b2   = blockIdx.y;
    const int tid  = threadIdx.x;
    const int lane = tid & 63, wave = tid >> 6;
    const int wr = wave >> 1, wc = wave & 1;
    const int ln = lane & 31, hi = lane >> 5;

    const float* Abase = t1 + (size_t)bRow * BM * ND;
    const float* Bbase = t2 + (size_t)b2 * NP * ND;

    f32x16 acc[2][4];
    #pragma unroll
    for (int mt = 0; mt < 2; ++mt)
        #pragma unroll
        for (int nt = 0; nt < 4; ++nt)
            #pragma unroll
            for (int r = 0; r < 16; ++r) acc[mt][nt][r] = 0.0f;

    for (int kc = 0; kc < 4; ++kc) {
        __syncthreads();
        #pragma unroll
        for (int i = 0; i < 4; ++i) {
            int flat = (i * 256 + tid) * 8;
            int r = flat >> 6, k0 = flat & 63;
            const float* gp = Abase + (size_t)r * ND + kc * BK + k0;
            float4 f0 = *reinterpret_cast<const float4*>(gp);
            float4 f1 = *reinterpret_cast<const float4*>(gp + 4);
            float s = inv1[bRow * BM + r];
            v8bf v = cvt8(f0, f1, s);
            int off = r * 128 + ((k0 * 2) ^ ((r & 7) << 4));
            *reinterpret_cast<v8bf*>(reinterpret_cast<char*>(Asb) + off) = v;
        }
        #pragma unroll
        for (int i = 0; i < 8; ++i) {
            int flat = (i * 256 + tid) * 8;
            int r = flat >> 6, k0 = flat & 63;
            v8bf v;
            if (r < NP) {
                const float* gp = Bbase + (size_t)r * ND + kc * BK + k0;
                float4 f0 = *reinterpret_cast<const float4*>(gp);
                float4 f1 = *reinterpret_cast<const float4*>(gp + 4);
                float s = inv2[b2 * NP + r];
                v = cvt8(f0, f1, s);
            } else {
                #pragma unroll
                for (int j = 0; j < 8; ++j) v[j] = (__bf16)0.0f;
            }
            int off = r * 128 + ((k0 * 2) ^ ((r & 7) << 4));
            *reinterpret_cast<v8bf*>(reinterpret_cast<char*>(Bsb) + off) = v;
        }
        __syncthreads();
        #pragma unroll
        for (int ks = 0; ks < 4; ++ks) {
            const int kb = ks * 32 + hi * 16;
            v8bf af[2], bfr[4];
            #pragma unroll
            for (int mt = 0; mt < 2; ++mt) {
                int r = wr * 64 + mt * 32 + ln;
                af[mt] = *reinterpret_cast<const v8bf*>(
                    reinterpret_cast<const char*>(Asb) + r * 128 + (kb ^ ((r & 7) << 4)));
            }
            #pragma unroll
            for (int nt = 0; nt < 4; ++nt) {
                int c = wc * 128 + nt * 32 + ln;
                bfr[nt] = *reinterpret_cast<const v8bf*>(
                    reinterpret_cast<const char*>(Bsb) + c * 128 + (kb ^ ((c & 7) << 4)));
            }
            #pragma unroll
            for (int mt = 0; mt < 2; ++mt)
                #pragma unroll
                for (int nt = 0; nt < 4; ++nt)
                    acc[mt][nt] = __builtin_amdgcn_mfma_f32_32x32x16_bf16(
                        af[mt], bfr[nt], acc[mt][nt], 0, 0, 0);
        }
    }

    #pragma unroll
    for (int mt = 0; mt < 2; ++mt) {
        float t[16];
        #pragma unroll
        for (int r = 0; r < 16; ++r) {
            float m = fmaxf(fmaxf(acc[mt][0][r], acc[mt][1][r]),
                            fmaxf(acc[mt][2][r], acc[mt][3][r]));
            #pragma unroll
            for (int off = 1; off <= 16; off <<= 1)
                m = fmaxf(m, __shfl_xor(m, off, 64));
            t[r] = m;
        }
        if (ln == 0) {
            #pragma unroll
            for (int r = 0; r < 16; ++r) {
                int row = wr * 64 + mt * 32 + (r & 3) + 8 * (r >> 2) + 4 * hi;
                rmx[wc][row] = t[r];
            }
        }
    }
    __syncthreads();
    if (tid < BM) {
        float m = fmaxf(rmx[0][tid], rmx[1][tid]);
        int grow = bRow * BM + tid;
        int b1 = grow / NP;
        int fb = (bRow * BM) / NP;
        float v0 = (b1 == fb) ? m : 0.0f;
        float v1 = (b1 != fb) ? m : 0.0f;
        #pragma unroll
        for (int off = 1; off < 64; off <<= 1) {
            v0 += __shfl_xor(v0, off, 64);
            v1 += __shfl_xor(v1, off, 64);
        }
        if (lane == 0) {
            atomicAdd(&sim12[fb * NB + b2], v0);
            int lb = (bRow * BM + BM - 1) / NP;
            if (lb != fb) atomicAdd(&sim12[lb * NB + b2], v1);
        }
    }
}

__global__ __launch_bounds__(256)
void filip_diag(const float* __restrict__ t1, const float* __restrict__ t2,
                const float* __restrict__ inv1, const float* __restrict__ inv2,
                float* __restrict__ out)
{
    const int b = blockIdx.x;
    const int tid = threadIdx.x;
    const int tx = tid & 15, ty = tid >> 4;

    __shared__ float As2[16][209];
    __shared__ float Bs2[16][65];
    __shared__ float colV[16][65];
    __shared__ int   colI[16][65];

    const float* Ap = t1 + (size_t)b * NP * ND;
    const float* Bp = t2 + (size_t)b * NP * ND;
    const float* ia = inv1 + b * NP;
    const float* ib = inv2 + b * NP;

    float rmax[13];
    int   ridx[13];
    #pragma unroll
    for (int m = 0; m < 13; ++m) { rmax[m] = -3.0e38f; ridx[m] = 1 << 30; }

    for (int tile = 0; tile < 4; ++tile) {
        float acc[13][4];
        #pragma unroll
        for (int m = 0; m < 13; ++m)
            #pragma unroll
            for (int n = 0; n < 4; ++n) acc[m][n] = 0.0f;

        for (int kk = 0; kk < 16; ++kk) {
            __syncthreads();
            #pragma unroll
            for (int i = 0; i < 13; ++i) {
                int e = tid + 256 * i;
                int p1 = e >> 4, k = e & 15;
                float v = 0.0f;
                if (p1 < NP) v = Ap[p1 * ND + kk * 16 + k] * ia[p1];
                As2[k][p1] = v;
            }
            #pragma unroll
            for (int i = 0; i < 4; ++i) {
                int e = tid + 256 * i;
                int pl = e >> 4, k = e & 15;
                int p2 = tile * 64 + pl;
                float v = 0.0f;
                if (p2 < NP) v = Bp[p2 * ND + kk * 16 + k] * ib[p2];
                Bs2[k][pl] = v;
            }
            __syncthreads();
            #pragma unroll 4
            for (int k = 0; k < 16; ++k) {
                float a[13], bq[4];
                #pragma unroll
                for (int m = 0; m < 13; ++m) a[m] = As2[k][ty + 16 * m];
                #pragma unroll
                for (int n = 0; n < 4; ++n) bq[n] = Bs2[k][tx + 16 * n];
                #pragma unroll
                for (int m = 0; m < 13; ++m)
                    #pragma unroll
                    for (int n = 0; n < 4; ++n)
                        acc[m][n] = fmaf(a[m], bq[n], acc[m][n]);
            }
        }

        #pragma unroll
        for (int n = 0; n < 4; ++n) {
            int c = tile * 64 + tx + 16 * n;
            if (c < NP) {
                #pragma unroll
                for (int m = 0; m < 13; ++m) {
                    float v = acc[m][n];
                    if (v > rmax[m] || (v == rmax[m] && c < ridx[m])) {
                        rmax[m] = v; ridx[m] = c;
                    }
                }
            }
        }

        #pragma unroll
        for (int n = 0; n < 4; ++n) {
            float bv = -3.0e38f; int bi = 1 << 30;
            #pragma unroll
            for (int m = 0; m < 13; ++m) {
                int row = ty + 16 * m;
                if (row < NP) {
                    float v = acc[m][n];
                    if (v > bv || (v == bv && row < bi)) { bv = v; bi = row; }
                }
            }
            colV[ty][tx + 16 * n] = bv;
            colI[ty][tx + 16 * n] = bi;
        }
        __syncthreads();
        if (tid < 64) {
            int c = tile * 64 + tid;
            if (c < NP) {
                float bv = -3.0e38f; int bi = 1 << 30;
                #pragma unroll
                for (int y = 0; y < 16; ++y) {
                    float v = colV[y][tid]; int i2 = colI[y][tid];
                    if (v > bv || (v == bv && i2 < bi)) { bv = v; bi = i2; }
                }
                out[1 + NBP + b * NP + c] = (float)bi;
            }
        }
        __syncthreads();
    }

    #pragma unroll
    for (int m = 0; m < 13; ++m) {
        float v = rmax[m]; int ix = ridx[m];
        #pragma unroll
        for (int off = 1; off < 16; off <<= 1) {
            float ov = __shfl_xor(v, off, 16);
            int   oi = __shfl_xor(ix, off, 16);
            if (ov > v || (ov == v && oi < ix)) { v = ov; ix = oi; }
        }
        rmax[m] = v; ridx[m] = ix;
    }
    if (tx == 0) {
        #pragma unroll
        for (int m = 0; m < 13; ++m) {
            int row = ty + 16 * m;
            if (row < NP) out[1 + b * NP + row] = (float)ridx[m];
        }
    }
}

// ---------------------------------------------------------------------------
extern "C" void kernel_launch(void* const* d_in, const int* in_sizes, int n_in,
                              void* d_out, int out_size, void* d_ws, size_t ws_size,
                              hipStream_t stream) {
    const float* t1 = (const float*)d_in[0];
    const float* t2 = (const float*)d_in[1];
    float* out = (float*)d_out;
    float* ws  = (float*)d_ws;

    float* inv1  = ws;
    float* inv2  = ws + NBP;
    float* sim12 = ws + 2 * NBP;

    if (ws_size >= (size_t)WS_NEED) {
        __bf16* t1bf = (__bf16*)((char*)d_ws + WS_T1BF);
        __bf16* t2bf = (__bf16*)((char*)d_ws + WS_T2BF);
        unsigned long long* parts = (unsigned long long*)((char*)d_ws + WS_PARTS);

        filip_prep3<<<2 * NBP / 4, 256, 0, stream>>>(t1, t2, inv1, inv2, sim12, t1bf, t2bf);
        filip_mfma4<<<dim3(98, NB), 256, 0, stream>>>(t1bf, t2bf, sim12);
        filip_diag4<<<dim3(4, NB), 256, 0, stream>>>(t1, t2, inv1, inv2, parts, out);
        filip_fin<<<49, 256, 0, stream>>>(parts, out);
        filip_loss<<<1, 64, 0, stream>>>(sim12, out);
    } else {
        filip_norms<<<2 * NBP, 64, 0, stream>>>(t1, t2, inv1, inv2, sim12);
        filip_mfma<<<dim3(98, NB), 256, 0, stream>>>(t1, t2, inv1, inv2, sim12);
        filip_diag<<<NB, 256, 0, stream>>>(t1, t2, inv1, inv2, out);
        filip_loss<<<1, 64, 0, stream>>>(sim12, out);
    }
}